// Round 10
// baseline (175.842 us; speedup 1.0000x reference)
//
#include <hip/hip_runtime.h>
#include <hip/hip_bf16.h>

#define B_SZ 16
#define IN_C 64
#define OUT_C 64
#define STYLE_DIM 512
#define HW 16384          // 128*128
#define HWT 256           // hw positions per block
#define EPS 1e-8f

// ---------------------------------------------------------------------------
// Fused StyleMod, one dispatch. Grid: 16 samples x 64 hw-tiles = 1024 blocks
// x 256 threads (4 blocks/CU, ~33 KB LDS each).
//
// R9 post-mortem: VALU floor is 13.6 us but wall was 82 us — ~5x memory-stall
// exposure; every x line was fetched 16x per block (8 o-groups x duplicated
// half-waves) and the reg-prefetch collapsed at the VGPR=128 cap.
// This version stages x through LDS in 8-channel chunks (reg->LDS double
// buffer, T14 async-split): each line fetched ONCE per block; stage loads for
// chunk k+1 issue before chunk k's 1024-cyc FMA block, so the vmcnt wait (at
// the ds_write) lands after the latency is already covered. x reads use a
// split-hw mapping (lane stride 16B) -> conflict-free ds_read_b128; w reads
// are half-wave-uniform broadcasts.
// ---------------------------------------------------------------------------
__global__ __launch_bounds__(256) void fused_kernel(
    const float* __restrict__ x,       // (B, IN_C, HW)
    const float* __restrict__ style,   // (B, STYLE_DIM)
    const float* __restrict__ weight,  // (OUT_C, IN_C)
    const float* __restrict__ bias,    // (OUT_C)
    const float* __restrict__ geo_w,   // (IN_C, STYLE_DIM)
    const float* __restrict__ geo_b,   // (IN_C)
    float* __restrict__ out)           // (B, OUT_C, HW)
{
    __shared__ float smod[IN_C];
    __shared__ float sWT[IN_C * OUT_C];   // [i][o], 16 KB
    __shared__ float xs[2][8][HWT];       // x chunk double-buffer, 2 x 8 KB

    const int tid = threadIdx.x;
    const int b   = blockIdx.x >> 6;            // 64 tiles per sample
    const int hwt = (blockIdx.x & 63) * HWT;

    // staging geometry: thread t owns channel (t>>5) of the chunk and hw
    // slots [(t&31)*4, +4) and [128+(t&31)*4, +4)  (split-hw, stride-16B)
    const int sch = tid >> 5;
    const int shw = (tid & 31) * 4;
    const float* xgb = x + ((size_t)b * IN_C + sch) * HW + hwt;

    // issue chunk-0 stage loads first: latency hides under phases 1+2
    float4 sa = *reinterpret_cast<const float4*>(xgb + shw);
    float4 sb = *reinterpret_cast<const float4*>(xgb + 128 + shw);

    // ---- phase 1: smod[i] = dot(style[b], geo_w[i]) + geo_b[i] + 1
    {
        const int i    = tid >> 2;
        const int part = tid & 3;
        const float4* st4 = reinterpret_cast<const float4*>(style + b * STYLE_DIM + part * 128);
        const float4* gw4 = reinterpret_cast<const float4*>(geo_w + i * STYLE_DIM + part * 128);
        float s = 0.0f;
        #pragma unroll
        for (int k = 0; k < 32; ++k) {
            const float4 a = st4[k];
            const float4 g = gw4[k];
            s = fmaf(a.x, g.x, s); s = fmaf(a.y, g.y, s);
            s = fmaf(a.z, g.z, s); s = fmaf(a.w, g.w, s);
        }
        s += __shfl_xor(s, 1);
        s += __shfl_xor(s, 2);
        if (part == 0) smod[i] = s + geo_b[i] + 1.0f;
    }
    __syncthreads();

    // ---- phase 2: demod + transposed weight tile; 4 threads per o
    {
        const int o    = tid >> 2;
        const int part = tid & 3;
        const float* wr = weight + o * IN_C + part * 16;
        const float* sm = smod + part * 16;
        float wv[16];
        float d = 0.0f;
        #pragma unroll
        for (int k = 0; k < 16; ++k) {
            wv[k] = wr[k] * sm[k];
            d = fmaf(wv[k], wv[k], d);
        }
        d += __shfl_xor(d, 1);
        d += __shfl_xor(d, 2);
        d = rsqrtf(d + EPS);
        #pragma unroll
        for (int k = 0; k < 16; ++k)
            sWT[(part * 16 + k) * OUT_C + o] = wv[k] * d;
    }

    // write staged chunk 0 (implicit vmcnt wait — long since satisfied)
    {
        float* dst = &xs[0][sch][0];
        *reinterpret_cast<float4*>(dst + shw)       = sa;
        *reinterpret_cast<float4*>(dst + 128 + shw) = sb;
    }
    __syncthreads();   // covers sWT writes + xs[0]

    // ---- phase 3: per-thread 8 o x 8 hw tile
    const int og  = (tid >> 5) * 8;         // o-group base (half-wave uniform)
    const int hwg = (tid & 31) * 4;         // split-hw: hwg and 128+hwg

    float acc[8][8];
    #pragma unroll
    for (int o = 0; o < 8; ++o)
        #pragma unroll
        for (int h = 0; h < 8; ++h) acc[o][h] = 0.0f;

#define COMPUTE_CHUNK(BUF, C0) do {                                          \
        _Pragma("unroll")                                                    \
        for (int cc = 0; cc < 8; ++cc) {                                     \
            const float4 xa = *reinterpret_cast<const float4*>(&xs[BUF][cc][hwg]);        \
            const float4 xc = *reinterpret_cast<const float4*>(&xs[BUF][cc][128 + hwg]);  \
            const float4 w0 = *reinterpret_cast<const float4*>(&sWT[((C0) + cc) * OUT_C + og]);     \
            const float4 w1 = *reinterpret_cast<const float4*>(&sWT[((C0) + cc) * OUT_C + og + 4]); \
            const float wv[8] = {w0.x, w0.y, w0.z, w0.w, w1.x, w1.y, w1.z, w1.w};        \
            const float xv[8] = {xa.x, xa.y, xa.z, xa.w, xc.x, xc.y, xc.z, xc.w};        \
            _Pragma("unroll")                                                \
            for (int o = 0; o < 8; ++o)                                      \
                _Pragma("unroll")                                            \
                for (int h = 0; h < 8; ++h)                                  \
                    acc[o][h] = fmaf(wv[o], xv[h], acc[o][h]);               \
        }                                                                    \
    } while (0)

    for (int c2 = 0; c2 < 4; ++c2) {
        const int cB = 2 * c2 + 1;
        // stage chunk cB (issue before compute; ~1024cy FMA covers latency)
        {
            const float* src = xgb + (size_t)cB * 8 * HW;
            sa = *reinterpret_cast<const float4*>(src + shw);
            sb = *reinterpret_cast<const float4*>(src + 128 + shw);
        }
        COMPUTE_CHUNK(0, 2 * c2 * 8);
        {
            float* dst = &xs[1][sch][0];
            *reinterpret_cast<float4*>(dst + shw)       = sa;
            *reinterpret_cast<float4*>(dst + 128 + shw) = sb;
        }
        __syncthreads();
        if (c2 < 3) {   // stage chunk cB+1
            const float* src = xgb + (size_t)(cB + 1) * 8 * HW;
            sa = *reinterpret_cast<const float4*>(src + shw);
            sb = *reinterpret_cast<const float4*>(src + 128 + shw);
        }
        COMPUTE_CHUNK(1, cB * 8);
        if (c2 < 3) {
            float* dst = &xs[0][sch][0];
            *reinterpret_cast<float4*>(dst + shw)       = sa;
            *reinterpret_cast<float4*>(dst + 128 + shw) = sb;
            __syncthreads();
        }
    }
#undef COMPUTE_CHUNK

    // ---- epilogue
    float* ob = out + ((size_t)b * OUT_C + og) * HW + hwt;
    #pragma unroll
    for (int o = 0; o < 8; ++o) {
        const float bv = bias[og + o];
        float4 r0, r1;
        r0.x = acc[o][0] + bv;  r0.y = acc[o][1] + bv;
        r0.z = acc[o][2] + bv;  r0.w = acc[o][3] + bv;
        r1.x = acc[o][4] + bv;  r1.y = acc[o][5] + bv;
        r1.z = acc[o][6] + bv;  r1.w = acc[o][7] + bv;
        *reinterpret_cast<float4*>(ob + (size_t)o * HW + hwg)       = r0;
        *reinterpret_cast<float4*>(ob + (size_t)o * HW + 128 + hwg) = r1;
    }
}

extern "C" void kernel_launch(void* const* d_in, const int* in_sizes, int n_in,
                              void* d_out, int out_size, void* d_ws, size_t ws_size,
                              hipStream_t stream) {
    const float* x      = (const float*)d_in[0];  // (16,64,128,128)
    const float* style  = (const float*)d_in[1];  // (16,512)
    const float* weight = (const float*)d_in[2];  // (1,64,64,1,1)
    const float* bias   = (const float*)d_in[3];  // (1,64)
    const float* geo_w  = (const float*)d_in[4];  // (64,512)
    const float* geo_b  = (const float*)d_in[5];  // (64)
    float* out = (float*)d_out;

    fused_kernel<<<B_SZ * (HW / HWT), 256, 0, stream>>>(
        x, style, weight, bias, geo_w, geo_b, out);
}

// Round 12
// 152.762 us; speedup vs baseline: 1.1511x; 1.1511x over previous
//
#include <hip/hip_runtime.h>
#include <hip/hip_bf16.h>

#define B_SZ 16
#define IN_C 64
#define OUT_C 64
#define STYLE_DIM 512
#define HW 16384          // 128*128
#define HWT 256           // hw positions per block
#define EPS 1e-8f

// ---------------------------------------------------------------------------
// Fused StyleMod, one dispatch. Grid: 16 x 64 = 1024 blocks x 256 threads,
// 4 blocks/CU (33 KB LDS, ~100 VGPR) -> WHOLE GRID RESIDENT, no 2nd round.
//
// R7/R9/R10 post-mortem: all stuck at 82-100us with ~80% stall because
// VGPR-staged prefetch gets de-pipelined by the compiler (loads sunk to
// just-before-use). Fix per the measured ladder (m93->m97, +69%): stage x
// with __builtin_amdgcn_global_load_lds (width 16, DMA direct to LDS, no
// VGPR round trip) in a 2-phase barrier pipeline: issue chunk k+1's DMA,
// compute chunk k from LDS, __syncthreads (its vmcnt(0)+barrier drain is
// exactly the needed wait). 8 chunks of 8 channels. Each x line fetched
// once per block. LDS dest is wave-uniform base + lane*16 (linear, m104).
// ---------------------------------------------------------------------------
__global__ __launch_bounds__(256) void fused_kernel(
    const float* __restrict__ x,       // (B, IN_C, HW)
    const float* __restrict__ style,   // (B, STYLE_DIM)
    const float* __restrict__ weight,  // (OUT_C, IN_C)
    const float* __restrict__ bias,    // (OUT_C)
    const float* __restrict__ geo_w,   // (IN_C, STYLE_DIM)
    const float* __restrict__ geo_b,   // (IN_C)
    float* __restrict__ out)           // (B, OUT_C, HW)
{
    __shared__ float smod[IN_C];
    __shared__ float sWT[IN_C * OUT_C];   // [i][o], 16 KB
    __shared__ float xs0[8][HWT];         // chunk double-buffer, 8 KB each
    __shared__ float xs1[8][HWT];

    const int tid  = threadIdx.x;
    const int b    = blockIdx.x >> 6;           // 64 tiles per sample
    const int hwt  = (blockIdx.x & 63) * HWT;
    const int wv   = tid >> 6;                  // wave id 0..3
    const int lane = tid & 63;

    // wave wv stages channels {2wv, 2wv+1} of each 8-channel chunk;
    // lane l supplies x[ch][hwt + 4l .. +3] -> LDS row base + 16l (linear).
    const float* xg0 = x + ((size_t)b * IN_C + 2 * wv) * HW + hwt + lane * 4;

#define STAGE(CH, XS) do {                                                   \
        __builtin_amdgcn_global_load_lds(                                    \
            (const __attribute__((address_space(1))) void*)(xg0 + (size_t)(CH) * 8 * HW),        \
            (__attribute__((address_space(3))) void*)&(XS)[2 * wv][0], 16, 0, 0);                \
        __builtin_amdgcn_global_load_lds(                                    \
            (const __attribute__((address_space(1))) void*)(xg0 + ((size_t)(CH) * 8 + 1) * HW),  \
            (__attribute__((address_space(3))) void*)&(XS)[2 * wv + 1][0], 16, 0, 0);            \
    } while (0)

    STAGE(0, xs0);   // chunk-0 DMA overlaps phases 1+2

    // ---- phase 1: smod[i] = dot(style[b], geo_w[i]) + geo_b[i] + 1
    {
        const int i    = tid >> 2;
        const int part = tid & 3;
        const float4* st4 = reinterpret_cast<const float4*>(style + b * STYLE_DIM + part * 128);
        const float4* gw4 = reinterpret_cast<const float4*>(geo_w + i * STYLE_DIM + part * 128);
        float s = 0.0f;
        #pragma unroll
        for (int k = 0; k < 32; ++k) {
            const float4 a = st4[k];
            const float4 g = gw4[k];
            s = fmaf(a.x, g.x, s); s = fmaf(a.y, g.y, s);
            s = fmaf(a.z, g.z, s); s = fmaf(a.w, g.w, s);
        }
        s += __shfl_xor(s, 1);
        s += __shfl_xor(s, 2);
        if (part == 0) smod[i] = s + geo_b[i] + 1.0f;
    }
    __syncthreads();

    // ---- phase 2: demod + transposed weight tile sWT[i][o]; 4 threads/o
    {
        const int o    = tid >> 2;
        const int part = tid & 3;
        const float* wr = weight + o * IN_C + part * 16;
        const float* sm = smod + part * 16;
        float wvv[16];
        float d = 0.0f;
        #pragma unroll
        for (int k = 0; k < 16; ++k) {
            wvv[k] = wr[k] * sm[k];
            d = fmaf(wvv[k], wvv[k], d);
        }
        d += __shfl_xor(d, 1);
        d += __shfl_xor(d, 2);
        d = rsqrtf(d + EPS);
        #pragma unroll
        for (int k = 0; k < 16; ++k)
            sWT[(part * 16 + k) * OUT_C + o] = wvv[k] * d;
    }
    __syncthreads();   // drains vmcnt(0): chunk 0 resident; sWT visible

    // ---- phase 3: per-thread 8 o x 8 hw tile
    const int og  = (tid >> 5) * 8;         // half-wave-uniform o-group
    const int hwg = (tid & 31) * 4;         // hw slots hwg and 128+hwg

    float acc[8][8];
    #pragma unroll
    for (int o = 0; o < 8; ++o)
        #pragma unroll
        for (int h = 0; h < 8; ++h) acc[o][h] = 0.0f;

#define COMPUTE_CHUNK(XS, C0) do {                                           \
        _Pragma("unroll")                                                    \
        for (int cc = 0; cc < 8; ++cc) {                                     \
            const float4 xa = *reinterpret_cast<const float4*>(&(XS)[cc][hwg]);        \
            const float4 xc = *reinterpret_cast<const float4*>(&(XS)[cc][128 + hwg]);  \
            const float4 w0 = *reinterpret_cast<const float4*>(&sWT[((C0) + cc) * OUT_C + og]);     \
            const float4 w1 = *reinterpret_cast<const float4*>(&sWT[((C0) + cc) * OUT_C + og + 4]); \
            const float wvv[8] = {w0.x, w0.y, w0.z, w0.w, w1.x, w1.y, w1.z, w1.w};     \
            const float xv[8]  = {xa.x, xa.y, xa.z, xa.w, xc.x, xc.y, xc.z, xc.w};     \
            _Pragma("unroll")                                                \
            for (int o = 0; o < 8; ++o)                                      \
                _Pragma("unroll")                                            \
                for (int h = 0; h < 8; ++h)                                  \
                    acc[o][h] = fmaf(wvv[o], xv[h], acc[o][h]);              \
        }                                                                    \
    } while (0)

    // 2-phase pipeline: stage next chunk, compute current, barrier (vmcnt(0)
    // drain inside __syncthreads is the wait). Static buffer ping-pong.
    #pragma unroll
    for (int cp = 0; cp < 4; ++cp) {
        const int cA = 2 * cp, cB = 2 * cp + 1;
        STAGE(cB, xs1);
        COMPUTE_CHUNK(xs0, cA * 8);
        __syncthreads();
        if (cB < 7) STAGE(cB + 1, xs0);
        COMPUTE_CHUNK(xs1, cB * 8);
        if (cB < 7) __syncthreads();
    }
#undef COMPUTE_CHUNK
#undef STAGE

    // ---- epilogue
    float* ob = out + ((size_t)b * OUT_C + og) * HW + hwt;
    #pragma unroll
    for (int o = 0; o < 8; ++o) {
        const float bv = bias[og + o];
        float4 r0, r1;
        r0.x = acc[o][0] + bv;  r0.y = acc[o][1] + bv;
        r0.z = acc[o][2] + bv;  r0.w = acc[o][3] + bv;
        r1.x = acc[o][4] + bv;  r1.y = acc[o][5] + bv;
        r1.z = acc[o][6] + bv;  r1.w = acc[o][7] + bv;
        *reinterpret_cast<float4*>(ob + (size_t)o * HW + hwg)       = r0;
        *reinterpret_cast<float4*>(ob + (size_t)o * HW + 128 + hwg) = r1;
    }
}

extern "C" void kernel_launch(void* const* d_in, const int* in_sizes, int n_in,
                              void* d_out, int out_size, void* d_ws, size_t ws_size,
                              hipStream_t stream) {
    const float* x      = (const float*)d_in[0];  // (16,64,128,128)
    const float* style  = (const float*)d_in[1];  // (16,512)
    const float* weight = (const float*)d_in[2];  // (1,64,64,1,1)
    const float* bias   = (const float*)d_in[3];  // (1,64)
    const float* geo_w  = (const float*)d_in[4];  // (64,512)
    const float* geo_b  = (const float*)d_in[5];  // (64)
    float* out = (float*)d_out;

    fused_kernel<<<B_SZ * (HW / HWT), 256, 0, stream>>>(
        x, style, weight, bias, geo_w, geo_b, out);
}